// Round 1
// baseline (517.527 us; speedup 1.0000x reference)
//
#include <hip/hip_runtime.h>
#include <hip/hip_bf16.h>

typedef unsigned int u32;
typedef unsigned short u16;
typedef __bf16 bf16x8 __attribute__((ext_vector_type(8)));
typedef float f32x4 __attribute__((ext_vector_type(4)));
typedef unsigned short u16x8 __attribute__((ext_vector_type(8)));

union BF8 { u16x8 u; bf16x8 b; };

#define CN 20000   // rows
#define CE 5000    // hyperedges
#define CD 128     // dim
#define CKS 20     // k-splits in main pass
#define CCHUNK 1024
#define CESTR 5120 // padded E stride for partials

// ---------------- K1: h = x @ W.T ----------------
__global__ __launch_bounds__(256) void k_h(const float* __restrict__ x,
                                           const float* __restrict__ W,
                                           float* __restrict__ h) {
  __shared__ __align__(16) float Wl[128 * 132];
  int t = threadIdx.x;
  for (int j = t; j < 128 * 128; j += 256) {
    int d = j >> 7, k = j & 127;
    Wl[d * 132 + k] = W[j];
  }
  __syncthreads();
  int n = blockIdx.x * 8 + (t >> 5);
  int dg = t & 31;
  float a0 = 0.f, a1 = 0.f, a2 = 0.f, a3 = 0.f;
  const float* xr = x + n * 128;
#pragma unroll 4
  for (int k = 0; k < 128; k += 4) {
    float4 xv = *(const float4*)(xr + k);
    float4 w0 = *(const float4*)(Wl + dg * 132 + k);
    float4 w1 = *(const float4*)(Wl + (dg + 32) * 132 + k);
    float4 w2 = *(const float4*)(Wl + (dg + 64) * 132 + k);
    float4 w3 = *(const float4*)(Wl + (dg + 96) * 132 + k);
    a0 += xv.x * w0.x + xv.y * w0.y + xv.z * w0.z + xv.w * w0.w;
    a1 += xv.x * w1.x + xv.y * w1.y + xv.z * w1.z + xv.w * w1.w;
    a2 += xv.x * w2.x + xv.y * w2.y + xv.z * w2.z + xv.w * w2.w;
    a3 += xv.x * w3.x + xv.y * w3.y + xv.z * w3.z + xv.w * w3.w;
  }
  float* hr = h + n * 128 + dg;
  hr[0] = a0; hr[32] = a1; hr[64] = a2; hr[96] = a3;
}

// ---------------- K2: sc[n] = (h[n]·u)/sqrt(128) ----------------
__global__ __launch_bounds__(256) void k_sc(const float* __restrict__ h,
                                            const float* __restrict__ u,
                                            float* __restrict__ sc) {
  int w = threadIdx.x >> 6, l = threadIdx.x & 63;
  int n = blockIdx.x * 4 + w;
  const float* hr = h + n * 128;
  float a = hr[l] * u[l] + hr[64 + l] * u[64 + l];
#pragma unroll
  for (int off = 32; off; off >>= 1) a += __shfl_down(a, off, 64);
  if (l == 0) sc[n] = a * 0.08838834764831845f;
}

// ---------------- K3: global max of sc ----------------
__global__ __launch_bounds__(1024) void k_max(const float* __restrict__ sc,
                                              float* __restrict__ mg) {
  __shared__ float red[1024];
  int t = threadIdx.x;
  float m = -1e30f;
  for (int i = t; i < CN; i += 1024) m = fmaxf(m, sc[i]);
  red[t] = m;
  __syncthreads();
  for (int s = 512; s; s >>= 1) {
    if (t < s) red[t] = fmaxf(red[t], red[t + s]);
    __syncthreads();
  }
  if (t == 0) mg[0] = red[0];
}

// ---------------- K4: p[n] = exp(sc-m); gT[d][n] = bf16(p*h) ----------------
__global__ __launch_bounds__(256) void k_gt(const float* __restrict__ h,
                                            const float* __restrict__ sc,
                                            const float* __restrict__ mg,
                                            float* __restrict__ p,
                                            u16* __restrict__ gT) {
  __shared__ __align__(16) float hl[64 * 132];
  __shared__ float pl[64];
  int t = threadIdx.x;
  int n0 = blockIdx.x * 64;
  int rows = (CN - n0 < 64) ? (CN - n0) : 64;   // 64 or 32
  float m = mg[0];
  for (int j = t; j < 2048; j += 256) {         // 64 rows x 32 float4
    int r = j >> 5, q = j & 31;
    float4 v = make_float4(0.f, 0.f, 0.f, 0.f);
    if (r < rows) v = *(const float4*)(h + (n0 + r) * 128 + q * 4);
    *(float4*)(hl + r * 132 + q * 4) = v;
  }
  if (t < 64) {
    float pv = (t < rows) ? __expf(sc[n0 + t] - m) : 0.f;
    pl[t] = pv;
    if (t < rows) p[n0 + t] = pv;
  }
  __syncthreads();
  int d = t >> 1, half = t & 1;
  if (half * 32 < rows) {
#pragma unroll
    for (int c = 0; c < 4; ++c) {
      u16x8 v;
#pragma unroll
      for (int ii = 0; ii < 8; ++ii) {
        int r = half * 32 + c * 8 + ii;
        float val = hl[r * 132 + d] * pl[r];
        __hip_bfloat16 bv = __float2bfloat16(val);
        union { __hip_bfloat16 b; u16 s; } cv; cv.b = bv;
        v[ii] = cv.s;
      }
      *(u16x8*)(gT + d * CN + n0 + half * 32 + c * 8) = v;
    }
  }
}

// ---------------- K5: main pass over H ----------------
// grid (40, 20): blockIdx.x = e-block (128 e's), blockIdx.y = k-split (1024 n's)
// Produces: bits2[be][n][4 words], Dpart[ks][e], numpart[ks][e][d]
__global__ __launch_bounds__(256) void k_main(const int* __restrict__ H,
                                              const u16* __restrict__ gT,
                                              const float* __restrict__ p,
                                              u32* __restrict__ bits2,
                                              float* __restrict__ Dpart,
                                              float* __restrict__ numpart) {
  __shared__ __align__(16) u32 bl[32][4];
  __shared__ __align__(16) u16 gl[128 * 40];    // 32 n x 128 d, row pad to 40
  __shared__ float pl[32];
  int t = threadIdx.x;
  int w = t >> 6, l = t & 63;
  int be = blockIdx.x;
  int ks = blockIdx.y;
  int e0 = be * 128;
  int nbase = ks * CCHUNK;
  int nend = nbase + CCHUNK; if (nend > CN) nend = CN;
  int rhalf = w >> 1, chalf = w & 1;

  f32x4 acc[2][8];
#pragma unroll
  for (int s = 0; s < 2; ++s)
#pragma unroll
    for (int dt = 0; dt < 8; ++dt) acc[s][dt] = (f32x4){0.f, 0.f, 0.f, 0.f};
  float Dacc = 0.f;

  for (int n0 = nbase; n0 < nend; n0 += 32) {
    if (t < 32) pl[t] = p[n0 + t];
    // ballots: each wave covers 16 (row, col-half) pairs
#pragma unroll 4
    for (int i = 0; i < 16; ++i) {
      int r = 2 * i + rhalf;
      int e = e0 + chalf * 64 + l;
      int hv = (e < CE) ? H[(n0 + r) * CE + e] : 0;
      unsigned long long b = __ballot(hv > 0);
      if (l == 0) { bl[r][chalf * 2] = (u32)b; bl[r][chalf * 2 + 1] = (u32)(b >> 32); }
    }
    // stage g tile: 128 d-rows x 32 n (64B/row) as 512 16B chunks
    for (int j = t; j < 512; j += 256) {
      int d = j >> 2, c = j & 3;
      *(u16x8*)(gl + d * 40 + c * 8) = *(const u16x8*)(gT + d * CN + n0 + c * 8);
    }
    __syncthreads();
    // bitmask out (coalesced 16B/row)
    if (t < 32) {
      uint4 bw = *(uint4*)&bl[t][0];
      *(uint4*)(bits2 + (be * CN + n0 + t) * 4) = bw;
    }
    // D accumulation: threads 0..127 <-> e-offset
    if (t < 128) {
      int wsel = t >> 5, bpos = t & 31;
      float d0 = 0.f;
#pragma unroll 8
      for (int r = 0; r < 32; ++r) {
        u32 wd = bl[r][wsel];
        d0 += ((wd >> bpos) & 1u) ? pl[r] : 0.f;
      }
      Dacc += d0;
    }
    // MFMA: wave w owns e-offsets [32w, 32w+32): 2 sub-tiles x 8 d-tiles
    bf16x8 afr[2];
#pragma unroll
    for (int s = 0; s < 2; ++s) {
      int bpos = 16 * s + (l & 15);
      int rb = (l >> 4) * 8;
      u16x8 av;
#pragma unroll
      for (int jj = 0; jj < 8; ++jj) {
        u32 wd = bl[rb + jj][w];
        av[jj] = ((wd >> bpos) & 1u) ? (u16)0x3F80 : (u16)0;
      }
      BF8 cv; cv.u = av; afr[s] = cv.b;
    }
#pragma unroll
    for (int dt = 0; dt < 8; ++dt) {
      bf16x8 bfr = *(const bf16x8*)(gl + (dt * 16 + (l & 15)) * 40 + (l >> 4) * 8);
      acc[0][dt] = __builtin_amdgcn_mfma_f32_16x16x32_bf16(afr[0], bfr, acc[0][dt], 0, 0, 0);
      acc[1][dt] = __builtin_amdgcn_mfma_f32_16x16x32_bf16(afr[1], bfr, acc[1][dt], 0, 0, 0);
    }
    __syncthreads();
  }
  // epilogue
  if (t < 128) {
    int e = e0 + t;
    if (e < CE) Dpart[ks * CESTR + e] = Dacc;
  }
#pragma unroll
  for (int s = 0; s < 2; ++s)
#pragma unroll
    for (int dt = 0; dt < 8; ++dt)
#pragma unroll
      for (int r = 0; r < 4; ++r) {
        int e = e0 + w * 32 + s * 16 + (l >> 4) * 4 + r;
        if (e < CE) {
          int d = dt * 16 + (l & 15);
          numpart[(ks * CESTR + e) * 128 + d] = acc[s][dt][r];
        }
      }
}

// ---------------- K6: reduce partials -> out0, invD ----------------
__global__ __launch_bounds__(128) void k_red(const float* __restrict__ numpart,
                                             const float* __restrict__ Dpart,
                                             float* __restrict__ out0,
                                             float* __restrict__ invD) {
  int e = blockIdx.x, d = threadIdx.x;
  float s = 0.f;
#pragma unroll
  for (int ks = 0; ks < CKS; ++ks) s += numpart[(ks * CESTR + e) * 128 + d];
  float D = 0.f;
#pragma unroll
  for (int ks = 0; ks < CKS; ++ks) D += Dpart[ks * CESTR + e];
  out0[e * 128 + d] = s / D;
  if (d == 0) invD[e] = 1.0f / D;
}

// ---------------- K7: A[n][e] = bit ? p[n]*invD[e] : 0 ----------------
__global__ __launch_bounds__(256) void k_aw(const u32* __restrict__ bits2,
                                            const float* __restrict__ p,
                                            const float* __restrict__ invD,
                                            float* __restrict__ A) {
  __shared__ u32 lb[16][160];
  __shared__ float pl[16];
  int t = threadIdx.x;
  int n0 = blockIdx.x * 16;
  for (int j = t; j < 2560; j += 256) {       // 40 wgroups x 16 rows x 4 words
    int wg = j >> 6, rem = j & 63;
    int row = rem >> 2, wo = rem & 3;
    lb[row][wg * 4 + wo] = bits2[(wg * CN + n0 + row) * 4 + wo];
  }
  if (t < 16) pl[t] = p[n0 + t];
  __syncthreads();
  for (int idx = t; idx < 16 * 1250; idx += 256) {
    int no = idx / 1250;
    int eq = idx - no * 1250;
    int e = eq * 4;
    u32 wd = lb[no][e >> 5];
    float pn = pl[no];
    float4 iv = *(const float4*)(invD + e);
    int sh = e & 31;
    float4 o;
    o.x = ((wd >> sh) & 1u) ? pn * iv.x : 0.f;
    o.y = ((wd >> (sh + 1)) & 1u) ? pn * iv.y : 0.f;
    o.z = ((wd >> (sh + 2)) & 1u) ? pn * iv.z : 0.f;
    o.w = ((wd >> (sh + 3)) & 1u) ? pn * iv.w : 0.f;
    *(float4*)(A + (n0 + no) * CE + e) = o;
  }
}

extern "C" void kernel_launch(void* const* d_in, const int* in_sizes, int n_in,
                              void* d_out, int out_size, void* d_ws, size_t ws_size,
                              hipStream_t stream) {
  const float* x = (const float*)d_in[0];
  const int*   H = (const int*)d_in[1];
  const float* W = (const float*)d_in[2];
  const float* u = (const float*)d_in[3];

  float* out0 = (float*)d_out;            // [E][128]
  float* Aout = out0 + CE * CD;           // [N][E]

  // big scratch inside the (not-yet-written) A region of d_out:
  float* numpart = Aout;                  // [20][5120][128] = 13.1M floats
  float* hbuf    = Aout + 16000000;       // [N][128]
  u16*   gT      = (u16*)(Aout + 20000000); // [128][N] bf16
  float* Dpart   = Aout + 24000000;       // [20][5120]

  // buffers that must survive the A-write live in d_ws:
  float* sc   = (float*)d_ws;             // [N]
  float* mg   = sc + 32768;               // [1]
  float* p    = sc + 65536;               // [N]
  float* invD = sc + 98304;               // [5120]
  u32*   bits2 = (u32*)(sc + 131072);     // [40][N][4] = 12.8 MB

  k_h  <<<dim3(2500), dim3(256), 0, stream>>>(x, W, hbuf);
  k_sc <<<dim3(5000), dim3(256), 0, stream>>>(hbuf, u, sc);
  k_max<<<dim3(1),    dim3(1024), 0, stream>>>(sc, mg);
  k_gt <<<dim3(313),  dim3(256), 0, stream>>>(hbuf, sc, mg, p, gT);
  k_main<<<dim3(40, 20), dim3(256), 0, stream>>>(H, gT, p, bits2, Dpart, numpart);
  k_red<<<dim3(CE),   dim3(128), 0, stream>>>(numpart, Dpart, out0, invD);
  k_aw <<<dim3(1250), dim3(256), 0, stream>>>(bits2, p, invD, Aout);
}

// Round 2
// 399.568 us; speedup vs baseline: 1.2952x; 1.2952x over previous
//
#include <hip/hip_runtime.h>
#include <hip/hip_bf16.h>

typedef unsigned int u32;
typedef unsigned short u16;
typedef __bf16 bf16x8 __attribute__((ext_vector_type(8)));
typedef float f32x4 __attribute__((ext_vector_type(4)));
typedef unsigned short u16x8 __attribute__((ext_vector_type(8)));

union BF8 { u16x8 u; bf16x8 b; };

#define CN 20000   // rows
#define CE 5000    // hyperedges
#define CD 128     // dim
#define CKS 25     // k-splits in MFMA pass (800 n each)
#define CESTR 5120 // padded E stride for partials
#define RPC 125    // rows per chunk in k_bits
#define NCHUNK 160 // 20000/125

// ---------------- K1: h = x @ W.T ----------------
__global__ __launch_bounds__(256) void k_h(const float* __restrict__ x,
                                           const float* __restrict__ W,
                                           float* __restrict__ h) {
  __shared__ __align__(16) float Wl[128 * 132];
  int t = threadIdx.x;
  for (int j = t; j < 128 * 128; j += 256) {
    int d = j >> 7, k = j & 127;
    Wl[d * 132 + k] = W[j];
  }
  __syncthreads();
  int n = blockIdx.x * 8 + (t >> 5);
  int dg = t & 31;
  float a0 = 0.f, a1 = 0.f, a2 = 0.f, a3 = 0.f;
  const float* xr = x + n * 128;
#pragma unroll 4
  for (int k = 0; k < 128; k += 4) {
    float4 xv = *(const float4*)(xr + k);
    float4 w0 = *(const float4*)(Wl + dg * 132 + k);
    float4 w1 = *(const float4*)(Wl + (dg + 32) * 132 + k);
    float4 w2 = *(const float4*)(Wl + (dg + 64) * 132 + k);
    float4 w3 = *(const float4*)(Wl + (dg + 96) * 132 + k);
    a0 += xv.x * w0.x + xv.y * w0.y + xv.z * w0.z + xv.w * w0.w;
    a1 += xv.x * w1.x + xv.y * w1.y + xv.z * w1.z + xv.w * w1.w;
    a2 += xv.x * w2.x + xv.y * w2.y + xv.z * w2.z + xv.w * w2.w;
    a3 += xv.x * w3.x + xv.y * w3.y + xv.z * w3.z + xv.w * w3.w;
  }
  float* hr = h + n * 128 + dg;
  hr[0] = a0; hr[32] = a1; hr[64] = a2; hr[96] = a3;
}

// ---------------- K2: sc[n] = (h[n]·u)/sqrt(128) ----------------
__global__ __launch_bounds__(256) void k_sc(const float* __restrict__ h,
                                            const float* __restrict__ u,
                                            float* __restrict__ sc) {
  int w = threadIdx.x >> 6, l = threadIdx.x & 63;
  int n = blockIdx.x * 4 + w;
  const float* hr = h + n * 128;
  float a = hr[l] * u[l] + hr[64 + l] * u[64 + l];
#pragma unroll
  for (int off = 32; off; off >>= 1) a += __shfl_down(a, off, 64);
  if (l == 0) sc[n] = a * 0.08838834764831845f;
}

// ---------------- K3: global max of sc ----------------
__global__ __launch_bounds__(1024) void k_max(const float* __restrict__ sc,
                                              float* __restrict__ mg) {
  __shared__ float red[1024];
  int t = threadIdx.x;
  float m = -1e30f;
  for (int i = t; i < CN; i += 1024) m = fmaxf(m, sc[i]);
  red[t] = m;
  __syncthreads();
  for (int s = 512; s; s >>= 1) {
    if (t < s) red[t] = fmaxf(red[t], red[t + s]);
    __syncthreads();
  }
  if (t == 0) mg[0] = red[0];
}

// ---------------- K4: p[n] = exp(sc-m); gT[d][n] = bf16(p*h) ----------------
__global__ __launch_bounds__(256) void k_gt(const float* __restrict__ h,
                                            const float* __restrict__ sc,
                                            const float* __restrict__ mg,
                                            float* __restrict__ p,
                                            u16* __restrict__ gT) {
  __shared__ __align__(16) float hl[64 * 132];
  __shared__ float pl[64];
  int t = threadIdx.x;
  int n0 = blockIdx.x * 64;
  int rows = (CN - n0 < 64) ? (CN - n0) : 64;
  float m = mg[0];
  for (int j = t; j < 2048; j += 256) {
    int r = j >> 5, q = j & 31;
    float4 v = make_float4(0.f, 0.f, 0.f, 0.f);
    if (r < rows) v = *(const float4*)(h + (n0 + r) * 128 + q * 4);
    *(float4*)(hl + r * 132 + q * 4) = v;
  }
  if (t < 64) {
    float pv = (t < rows) ? __expf(sc[n0 + t] - m) : 0.f;
    pl[t] = pv;
    if (t < rows) p[n0 + t] = pv;
  }
  __syncthreads();
  int d = t >> 1, half = t & 1;
  if (half * 32 < rows) {
#pragma unroll
    for (int c = 0; c < 4; ++c) {
      u16x8 v;
#pragma unroll
      for (int ii = 0; ii < 8; ++ii) {
        int r = half * 32 + c * 8 + ii;
        float val = hl[r * 132 + d] * pl[r];
        __hip_bfloat16 bv = __float2bfloat16(val);
        union { __hip_bfloat16 b; u16 s; } cv; cv.b = bv;
        v[ii] = cv.s;
      }
      *(u16x8*)(gT + (size_t)d * CN + n0 + half * 32 + c * 8) = v;
    }
  }
}

// ---------------- K5: stream H -> interleaved bitmask + D partials ----------------
// grid (5, 160): wave w of block x handles e-segment seg = x*4+w (256 e's),
// rows [y*125, y*125+125). Bits layout per row: 160 u32 words; group g (8 words)
// covers e in [256g, 256g+256) as [B0.lo,B0.hi,B1.lo,B1.hi,B2.lo,B2.hi,B3.lo,B3.hi]
// where B_b bit l is mask for e = 256g + 4l + b.
__global__ __launch_bounds__(256) void k_bits(const int* __restrict__ H,
                                              const float* __restrict__ p,
                                              u32* __restrict__ bits,
                                              float* __restrict__ DpartA) {
  int t = threadIdx.x;
  int w = t >> 6, l = t & 63;
  int seg = blockIdx.x * 4 + w;            // 0..19
  int chunk = blockIdx.y;                  // 0..159
  int n0 = chunk * RPC;
  int ebase = seg * 256 + l * 4;
  bool evalid = ebase < CE;                // CE%4==0 -> all 4 components valid
  float d0 = 0.f, d1 = 0.f, d2 = 0.f, d3 = 0.f;
  const int* Hp = H + (size_t)n0 * CE + ebase;
  int b = l >> 1, hf = l & 1;              // for word store (lanes 0..7)
#pragma unroll 4
  for (int r = 0; r < RPC; ++r) {
    int4 hv = make_int4(0, 0, 0, 0);
    if (evalid) hv = *(const int4*)(Hp + (size_t)r * CE);
    float pv = p[n0 + r];
    bool p0 = hv.x > 0, p1 = hv.y > 0, p2 = hv.z > 0, p3 = hv.w > 0;
    unsigned long long B0 = __ballot(p0);
    unsigned long long B1 = __ballot(p1);
    unsigned long long B2 = __ballot(p2);
    unsigned long long B3 = __ballot(p3);
    d0 += p0 ? pv : 0.f;
    d1 += p1 ? pv : 0.f;
    d2 += p2 ? pv : 0.f;
    d3 += p3 ? pv : 0.f;
    if (l < 8) {
      unsigned long long s01 = (b & 1) ? B1 : B0;
      unsigned long long s23 = (b & 1) ? B3 : B2;
      unsigned long long Bb = (b & 2) ? s23 : s01;
      u32 word = (u32)(Bb >> (32 * hf));
      bits[(size_t)(n0 + r) * 160 + seg * 8 + l] = word;
    }
  }
  float* dp = DpartA + (size_t)chunk * CESTR + ebase;
  dp[0] = d0; dp[1] = d1; dp[2] = d2; dp[3] = d3;
}

// ---------------- K6: MFMA pass: numpart[ks][e][d] from bits + gT ----------------
// grid (40, 25): be = e-block of 128, ks = n-split of 800 rows.
__global__ __launch_bounds__(256) void k_mm(const u32* __restrict__ bits,
                                            const u16* __restrict__ gT,
                                            float* __restrict__ numpart) {
  __shared__ u32 bl4[32][5];               // pad 5: conflict-free A-frag reads
  __shared__ __align__(16) u16 gl[128 * 40];
  int t = threadIdx.x;
  int w = t >> 6, l = t & 63;
  int be = blockIdx.x, ks = blockIdx.y;
  int e0 = be * 128;
  int nbase = ks * 800;
  int sgrp8 = (be >> 1) * 8, par = be & 1;

  f32x4 acc[2][8];
#pragma unroll
  for (int s = 0; s < 2; ++s)
#pragma unroll
    for (int dt = 0; dt < 8; ++dt) acc[s][dt] = (f32x4){0.f, 0.f, 0.f, 0.f};

  for (int n0 = nbase; n0 < nbase + 800; n0 += 32) {
    // stage g tile: 128 d-rows x 32 n
    for (int j = t; j < 512; j += 256) {
      int d = j >> 2, c = j & 3;
      *(u16x8*)(gl + d * 40 + c * 8) = *(const u16x8*)(gT + (size_t)d * CN + n0 + c * 8);
    }
    // bits: 32 rows x 4 interleaved words (this be's half)
    if (t < 128) {
      int r = t >> 2, j = t & 3;
      bl4[r][j] = bits[(size_t)(n0 + r) * 160 + sgrp8 + j * 2 + par];
    }
    __syncthreads();
    bf16x8 afr[2];
    int rb = (l >> 4) * 8;
    int posbase = 8 * w + ((l >> 2) & 3);
#pragma unroll
    for (int s = 0; s < 2; ++s) {
      int pos = posbase + 4 * s;
      u16x8 av;
#pragma unroll
      for (int jj = 0; jj < 8; ++jj) {
        u32 wd = bl4[rb + jj][l & 3];
        av[jj] = ((wd >> pos) & 1u) ? (u16)0x3F80 : (u16)0;
      }
      BF8 cv; cv.u = av; afr[s] = cv.b;
    }
#pragma unroll
    for (int dt = 0; dt < 8; ++dt) {
      bf16x8 bfr = *(const bf16x8*)(gl + (dt * 16 + (l & 15)) * 40 + (l >> 4) * 8);
      acc[0][dt] = __builtin_amdgcn_mfma_f32_16x16x32_bf16(afr[0], bfr, acc[0][dt], 0, 0, 0);
      acc[1][dt] = __builtin_amdgcn_mfma_f32_16x16x32_bf16(afr[1], bfr, acc[1][dt], 0, 0, 0);
    }
    __syncthreads();
  }
#pragma unroll
  for (int s = 0; s < 2; ++s)
#pragma unroll
    for (int dt = 0; dt < 8; ++dt)
#pragma unroll
      for (int r = 0; r < 4; ++r) {
        int e = e0 + w * 32 + s * 16 + (l >> 4) * 4 + r;   // < 5120, in-bounds
        int d = dt * 16 + (l & 15);
        numpart[((size_t)ks * CESTR + e) * 128 + d] = acc[s][dt][r];
      }
}

// ---------------- K7: reduce D partials -> Dfull, invD ----------------
__global__ __launch_bounds__(256) void k_dred(const float* __restrict__ DpartA,
                                              float* __restrict__ Dfull,
                                              float* __restrict__ invD) {
  int e = blockIdx.x * 256 + threadIdx.x;  // < 5120
  float s = 0.f;
  for (int c = 0; c < NCHUNK; ++c) s += DpartA[(size_t)c * CESTR + e];
  Dfull[e] = s;
  invD[e] = 1.0f / s;
}

// ---------------- K8: reduce numpart -> out0 ----------------
__global__ __launch_bounds__(128) void k_red(const float* __restrict__ numpart,
                                             const float* __restrict__ Dfull,
                                             float* __restrict__ out0) {
  int e = blockIdx.x, d = threadIdx.x;
  float s = 0.f;
#pragma unroll
  for (int ks = 0; ks < CKS; ++ks) s += numpart[((size_t)ks * CESTR + e) * 128 + d];
  out0[e * 128 + d] = s / Dfull[e];
}

// ---------------- K9: A[n][e] = bit ? p[n]*invD[e] : 0 ----------------
__global__ __launch_bounds__(256) void k_aw(const u32* __restrict__ bits,
                                            const float* __restrict__ p,
                                            const float* __restrict__ invD,
                                            float* __restrict__ A) {
  __shared__ u32 lb[16][160];
  __shared__ float pl[16];
  int t = threadIdx.x;
  int n0 = blockIdx.x * 16;
  for (int j = t; j < 2560; j += 256) {     // 16 rows x 160 words, coalesced
    int row = j / 160, wrd = j - row * 160;
    lb[row][wrd] = bits[(size_t)(n0 + row) * 160 + wrd];
  }
  if (t < 16) pl[t] = p[n0 + t];
  __syncthreads();
  for (int idx = t; idx < 16 * 1250; idx += 256) {
    int no = idx / 1250;
    int q = idx - no * 1250;                // 4-e group: e = 4q..4q+3
    int g = q >> 6, hf = (q >> 5) & 1, pos = q & 31;
    int base = g * 8 + hf;
    u32 w0 = lb[no][base];
    u32 w1 = lb[no][base + 2];
    u32 w2 = lb[no][base + 4];
    u32 w3 = lb[no][base + 6];
    float pn = pl[no];
    float4 iv = *(const float4*)(invD + q * 4);
    float4 o;
    o.x = ((w0 >> pos) & 1u) ? pn * iv.x : 0.f;
    o.y = ((w1 >> pos) & 1u) ? pn * iv.y : 0.f;
    o.z = ((w2 >> pos) & 1u) ? pn * iv.z : 0.f;
    o.w = ((w3 >> pos) & 1u) ? pn * iv.w : 0.f;
    *(float4*)(A + (size_t)(n0 + no) * CE + q * 4) = o;
  }
}

extern "C" void kernel_launch(void* const* d_in, const int* in_sizes, int n_in,
                              void* d_out, int out_size, void* d_ws, size_t ws_size,
                              hipStream_t stream) {
  const float* x = (const float*)d_in[0];
  const int*   H = (const int*)d_in[1];
  const float* W = (const float*)d_in[2];
  const float* u = (const float*)d_in[3];

  float* out0 = (float*)d_out;              // [E][128]
  float* Aout = out0 + CE * CD;             // [N][E]

  // big scratch inside the (not-yet-written) A region of d_out:
  float* numpart = Aout;                    // 25*5120*128 = 16,384,000 floats
  float* hbuf    = Aout + 16500000;         // [N][128] = 2,560,000
  u16*   gT      = (u16*)(Aout + 19200000); // [128][N] bf16 = 1,280,000 floats
  float* DpartA  = Aout + 20600000;         // [160][5120] = 819,200

  // buffers that must survive until k_aw live in d_ws:
  float* sc    = (float*)d_ws;              // [N]
  float* mg    = sc + 32768;                // [1]
  float* p     = sc + 65536;                // [N]
  float* invD  = sc + 98304;                // [5120]
  float* Dfull = sc + 110592;               // [5120]
  u32*   bits  = (u32*)(sc + 131072);       // [N][160] u32 = 12.8 MB

  k_h   <<<dim3(2500),    dim3(256),  0, stream>>>(x, W, hbuf);
  k_sc  <<<dim3(5000),    dim3(256),  0, stream>>>(hbuf, u, sc);
  k_max <<<dim3(1),       dim3(1024), 0, stream>>>(sc, mg);
  k_gt  <<<dim3(313),     dim3(256),  0, stream>>>(hbuf, sc, mg, p, gT);
  k_bits<<<dim3(5, 160),  dim3(256),  0, stream>>>(H, p, bits, DpartA);
  k_mm  <<<dim3(40, 25),  dim3(256),  0, stream>>>(bits, gT, numpart);
  k_dred<<<dim3(20),      dim3(256),  0, stream>>>(DpartA, Dfull, invD);
  k_red <<<dim3(5000),    dim3(128),  0, stream>>>(numpart, Dfull, out0);
  k_aw  <<<dim3(1250),    dim3(256),  0, stream>>>(bits, p, invD, Aout);
}

// Round 3
// 302.350 us; speedup vs baseline: 1.7117x; 1.3215x over previous
//
#include <hip/hip_runtime.h>
#include <hip/hip_bf16.h>

typedef unsigned int u32;
typedef unsigned short u16;
typedef __bf16 bf16x8 __attribute__((ext_vector_type(8)));
typedef float f32x4 __attribute__((ext_vector_type(4)));
typedef unsigned short u16x8 __attribute__((ext_vector_type(8)));
typedef int i32x4 __attribute__((ext_vector_type(4)));

union BF8 { u16x8 u; bf16x8 b; };

#define CN 20000   // rows
#define CE 5000    // hyperedges
#define CD 128     // dim
#define NW 625     // 32-row windows (20000/32)
#define EW 5120    // padded e stride
#define CKS 25     // k-splits in MFMA pass (25 windows = 800 rows each)

// ---------------- K1: h = x @ W.T, fused sc + per-block max ----------------
__global__ __launch_bounds__(256) void k_h(const float* __restrict__ x,
                                           const float* __restrict__ W,
                                           float* __restrict__ h,
                                           float* __restrict__ sc,
                                           float* __restrict__ mgpart) {
  __shared__ __align__(16) float Wl[128 * 132];
  __shared__ float ul[128];
  __shared__ float red8[8];
  int t = threadIdx.x;
  for (int j = t; j < 128 * 128; j += 256) {
    int d = j >> 7, k = j & 127;
    Wl[d * 132 + k] = W[j];
  }
  __syncthreads();
  int rg = t >> 5;                       // row group 0..7
  int n = blockIdx.x * 8 + rg;
  int dg = t & 31;
  float a0 = 0.f, a1 = 0.f, a2 = 0.f, a3 = 0.f;
  const float* xr = x + n * 128;
#pragma unroll 4
  for (int k = 0; k < 128; k += 4) {
    float4 xv = *(const float4*)(xr + k);
    float4 w0 = *(const float4*)(Wl + dg * 132 + k);
    float4 w1 = *(const float4*)(Wl + (dg + 32) * 132 + k);
    float4 w2 = *(const float4*)(Wl + (dg + 64) * 132 + k);
    float4 w3 = *(const float4*)(Wl + (dg + 96) * 132 + k);
    a0 += xv.x * w0.x + xv.y * w0.y + xv.z * w0.z + xv.w * w0.w;
    a1 += xv.x * w1.x + xv.y * w1.y + xv.z * w1.z + xv.w * w1.w;
    a2 += xv.x * w2.x + xv.y * w2.y + xv.z * w2.z + xv.w * w2.w;
    a3 += xv.x * w3.x + xv.y * w3.y + xv.z * w3.z + xv.w * w3.w;
  }
  // stage u once (race-free: written before first use via barrier below)
  if (blockIdx.x >= 0) {
    if (t < 128) ul[t] = 0.f;  // placeholder to keep shape; real load next line
  }
  if (t < 128) ul[t] = __ldg(&x[0]) * 0.f + 0.f;  // dummy init removed below
  __syncthreads();
  float* hr = h + n * 128 + dg;
  hr[0] = a0; hr[32] = a1; hr[64] = a2; hr[96] = a3;
  // sc: need u — reload directly from global (L2-hot, broadcast)
  const float* ug = (const float*)nullptr;
  (void)ug;
  float scp = 0.f;
  // u passed via Wl reuse is unsafe; use global loads (uniform per lane group)
  scp = a0 * __ldg(&h[0]) * 0.f; // overwritten below
  scp = 0.f;
  scp += a0 * sc[-0]; // placeholder — replaced: see k_h2 comment
  (void)scp;
  red8[0] = 0.f;
  __syncthreads();
  if (t == 0) mgpart[blockIdx.x] = -1e30f;
}

// NOTE: k_h above intentionally neutered for sc (see k_h2 which does it properly).
// ---------------- K1 (real): h + sc + block max ----------------
__global__ __launch_bounds__(256) void k_h2(const float* __restrict__ x,
                                            const float* __restrict__ W,
                                            const float* __restrict__ u,
                                            float* __restrict__ h,
                                            float* __restrict__ sc,
                                            float* __restrict__ mgpart) {
  __shared__ __align__(16) float Wl[128 * 132];
  __shared__ float ul[128];
  __shared__ float red8[8];
  int t = threadIdx.x;
  if (t < 128) ul[t] = u[t];
  for (int j = t; j < 128 * 128; j += 256) {
    int d = j >> 7, k = j & 127;
    Wl[d * 132 + k] = W[j];
  }
  __syncthreads();
  int rg = t >> 5;
  int n = blockIdx.x * 8 + rg;
  int dg = t & 31;
  float a0 = 0.f, a1 = 0.f, a2 = 0.f, a3 = 0.f;
  const float* xr = x + n * 128;
#pragma unroll 4
  for (int k = 0; k < 128; k += 4) {
    float4 xv = *(const float4*)(xr + k);
    float4 w0 = *(const float4*)(Wl + dg * 132 + k);
    float4 w1 = *(const float4*)(Wl + (dg + 32) * 132 + k);
    float4 w2 = *(const float4*)(Wl + (dg + 64) * 132 + k);
    float4 w3 = *(const float4*)(Wl + (dg + 96) * 132 + k);
    a0 += xv.x * w0.x + xv.y * w0.y + xv.z * w0.z + xv.w * w0.w;
    a1 += xv.x * w1.x + xv.y * w1.y + xv.z * w1.z + xv.w * w1.w;
    a2 += xv.x * w2.x + xv.y * w2.y + xv.z * w2.z + xv.w * w2.w;
    a3 += xv.x * w3.x + xv.y * w3.y + xv.z * w3.z + xv.w * w3.w;
  }
  float* hr = h + n * 128 + dg;
  hr[0] = a0; hr[32] = a1; hr[64] = a2; hr[96] = a3;
  float scp = a0 * ul[dg] + a1 * ul[dg + 32] + a2 * ul[dg + 64] + a3 * ul[dg + 96];
#pragma unroll
  for (int off = 16; off; off >>= 1) scp += __shfl_down(scp, off, 32);
  if (dg == 0) {
    float sv = scp * 0.08838834764831845f;
    sc[n] = sv;
    red8[rg] = sv;
  }
  __syncthreads();
  if (t == 0) {
    float m = red8[0];
#pragma unroll
    for (int i = 1; i < 8; ++i) m = fmaxf(m, red8[i]);
    mgpart[blockIdx.x] = m;
  }
}

// ---------------- K2: reduce per-block maxes ----------------
__global__ __launch_bounds__(256) void k_max2(const float* __restrict__ mgpart,
                                              float* __restrict__ mg) {
  __shared__ float red[256];
  int t = threadIdx.x;
  float m = -1e30f;
  for (int i = t; i < 2500; i += 256) m = fmaxf(m, mgpart[i]);
  red[t] = m;
  __syncthreads();
  for (int s = 128; s; s >>= 1) {
    if (t < s) red[t] = fmaxf(red[t], red[t + s]);
    __syncthreads();
  }
  if (t == 0) mg[0] = red[0];
}

// ---------------- K3: H -> bitsT[nw][e] (bit j = mask of row nw*32+j) ----------------
__global__ __launch_bounds__(256) void k_bits(const int* __restrict__ H,
                                              u32* __restrict__ bitsT) {
  int t = threadIdx.x, w = t >> 6, l = t & 63;
  int g = blockIdx.x * 4 + w;                // 0..4095
  for (int task = g; task < 12500; task += 4096) {
    int nw = task / 20;
    int seg = task - nw * 20;
    int ebase = seg * 256 + l * 4;
    u32 b0 = 0, b1 = 0, b2 = 0, b3 = 0;
    if (ebase < CE) {                        // CE%4==0: all 4 comps valid
      const int* Hb = H + (size_t)nw * 32 * CE + ebase;
      i32x4 c[8];
#pragma unroll
      for (int j = 0; j < 8; ++j)
        c[j] = __builtin_nontemporal_load((const i32x4*)(Hb + (size_t)j * CE));
#pragma unroll
      for (int r = 0; r < 32; r += 8) {
        i32x4 nx[8];
        if (r + 8 < 32) {
#pragma unroll
          for (int j = 0; j < 8; ++j)
            nx[j] = __builtin_nontemporal_load((const i32x4*)(Hb + (size_t)(r + 8 + j) * CE));
        }
#pragma unroll
        for (int j = 0; j < 8; ++j) {        // H in {0,1}: bit = value
          b0 |= ((u32)c[j].x) << (r + j);
          b1 |= ((u32)c[j].y) << (r + j);
          b2 |= ((u32)c[j].z) << (r + j);
          b3 |= ((u32)c[j].w) << (r + j);
        }
        if (r + 8 < 32) {
#pragma unroll
          for (int j = 0; j < 8; ++j) c[j] = nx[j];
        }
      }
    }
    uint4 bw; bw.x = b0; bw.y = b1; bw.z = b2; bw.w = b3;
    *(uint4*)(bitsT + (size_t)nw * EW + ebase) = bw;
  }
}

// ---------------- K4: p = exp(sc-m); gTt[nw][d][32] = bf16(p*h) ----------------
__global__ __launch_bounds__(256) void k_gt(const float* __restrict__ h,
                                            const float* __restrict__ sc,
                                            const float* __restrict__ mg,
                                            float* __restrict__ p,
                                            u16* __restrict__ gTt) {
  __shared__ __align__(16) float hl[32 * 132];
  __shared__ float pl[32];
  int t = threadIdx.x;
  int nw = blockIdx.x;
  int n0 = nw * 32;
  float m = mg[0];
  for (int k = 0; k < 4; ++k) {
    int idx = t + k * 256;                  // 1024 float4 total
    int r = idx >> 5, c = idx & 31;
    *(float4*)(hl + r * 132 + c * 4) = *(const float4*)(h + (size_t)(n0 + r) * 128 + c * 4);
  }
  if (t < 32) {
    float pv = __expf(sc[n0 + t] - m);
    pl[t] = pv;
    p[n0 + t] = pv;
  }
  __syncthreads();
  int d = t >> 1, nh = t & 1;
  u16x8 v0, v1;
#pragma unroll
  for (int i = 0; i < 8; ++i) {
    int r = nh * 16 + i;
    union { __hip_bfloat16 b; u16 s; } cv;
    cv.b = __float2bfloat16(hl[r * 132 + d] * pl[r]);
    v0[i] = cv.s;
  }
#pragma unroll
  for (int i = 0; i < 8; ++i) {
    int r = nh * 16 + 8 + i;
    union { __hip_bfloat16 b; u16 s; } cv;
    cv.b = __float2bfloat16(hl[r * 132 + d] * pl[r]);
    v1[i] = cv.s;
  }
  u16* dst = gTt + (size_t)nw * 4096 + d * 32 + nh * 16;
  *(u16x8*)dst = v0;
  *(u16x8*)(dst + 8) = v1;
}

// ---------------- K5: D partials from bitsT + p ----------------
__global__ __launch_bounds__(256) void k_dred(const u32* __restrict__ bitsT,
                                              const float* __restrict__ p,
                                              float* __restrict__ Dp2) {
  int e = blockIdx.x * 256 + threadIdx.x;    // < 5120
  int s = blockIdx.y;                        // 0..9
  int wbeg = s * 62 + (s < 5 ? s : 5);
  int wcnt = 62 + (s < 5 ? 1 : 0);
  float d = 0.f;
  for (int k = 0; k < wcnt; ++k) {
    int wi = wbeg + k;
    u32 word = bitsT[(size_t)wi * EW + e];
    const f32x4* pp = (const f32x4*)(p + wi * 32);
#pragma unroll
    for (int c = 0; c < 8; ++c) {
      f32x4 pv = pp[c];
      d += (float)((word >> (4 * c)) & 1u) * pv[0];
      d += (float)((word >> (4 * c + 1)) & 1u) * pv[1];
      d += (float)((word >> (4 * c + 2)) & 1u) * pv[2];
      d += (float)((word >> (4 * c + 3)) & 1u) * pv[3];
    }
  }
  Dp2[(size_t)s * EW + e] = d;
}

// ---------------- K6: MFMA pass: numpart[ks][e][d] ----------------
__global__ __launch_bounds__(256) void k_mm(const u32* __restrict__ bitsT,
                                            const u16* __restrict__ gTt,
                                            float* __restrict__ numpart) {
  __shared__ u32 wl[128];
  __shared__ __align__(16) u16 gl[128 * 40];
  int t = threadIdx.x;
  int w = t >> 6, l = t & 63;
  int be = blockIdx.x, ks = blockIdx.y;
  int e0 = be * 128;

  f32x4 acc[2][8];
#pragma unroll
  for (int s = 0; s < 2; ++s)
#pragma unroll
    for (int dt = 0; dt < 8; ++dt) acc[s][dt] = (f32x4){0.f, 0.f, 0.f, 0.f};

  for (int wi = ks * 25; wi < ks * 25 + 25; ++wi) {
    if (t < 32) *(uint4*)&wl[t * 4] = *(const uint4*)(bitsT + (size_t)wi * EW + e0 + t * 4);
    {
      const u16* src = gTt + (size_t)wi * 4096 + (t >> 1) * 32 + (t & 1) * 16;
      u16x8 v0 = *(const u16x8*)src;
      u16x8 v1 = *(const u16x8*)(src + 8);
      u16* dst = gl + (t >> 1) * 40 + (t & 1) * 16;
      *(u16x8*)dst = v0;
      *(u16x8*)(dst + 8) = v1;
    }
    __syncthreads();
    int rb = (l >> 4) * 8;
    u32 w0 = wl[32 * w + (l & 15)];
    u32 w1 = wl[32 * w + 16 + (l & 15)];
    BF8 cv0, cv1;
#pragma unroll
    for (int jj = 0; jj < 8; ++jj) {
      cv0.u[jj] = (u16)(((w0 >> (rb + jj)) & 1u) * 0x3F80u);
      cv1.u[jj] = (u16)(((w1 >> (rb + jj)) & 1u) * 0x3F80u);
    }
#pragma unroll
    for (int dt = 0; dt < 8; ++dt) {
      bf16x8 bfr = *(const bf16x8*)(gl + (dt * 16 + (l & 15)) * 40 + (l >> 4) * 8);
      acc[0][dt] = __builtin_amdgcn_mfma_f32_16x16x32_bf16(cv0.b, bfr, acc[0][dt], 0, 0, 0);
      acc[1][dt] = __builtin_amdgcn_mfma_f32_16x16x32_bf16(cv1.b, bfr, acc[1][dt], 0, 0, 0);
    }
    __syncthreads();
  }
#pragma unroll
  for (int s = 0; s < 2; ++s)
#pragma unroll
    for (int dt = 0; dt < 8; ++dt)
#pragma unroll
      for (int r = 0; r < 4; ++r) {
        int e = e0 + w * 32 + s * 16 + (l >> 4) * 4 + r;
        int d = dt * 16 + (l & 15);
        numpart[((size_t)ks * EW + e) * 128 + d] = acc[s][dt][r];
      }
}

// ---------------- K7: reduce -> out0, invD ----------------
__global__ __launch_bounds__(128) void k_red(const float* __restrict__ numpart,
                                             const float* __restrict__ Dp2,
                                             float* __restrict__ out0,
                                             float* __restrict__ invD) {
  int e = blockIdx.x, d = threadIdx.x;
  float s = 0.f;
#pragma unroll
  for (int ks = 0; ks < CKS; ++ks) s += numpart[((size_t)ks * EW + e) * 128 + d];
  float D = 0.f;
#pragma unroll
  for (int q = 0; q < 10; ++q) D += Dp2[(size_t)q * EW + e];
  out0[e * 128 + d] = s / D;
  if (d == 0) invD[e] = 1.0f / D;
}

// ---------------- K8: A[n][e] = bit ? p[n]*invD[e] : 0 ----------------
__global__ __launch_bounds__(256) void k_aw(const u32* __restrict__ bitsT,
                                            const float* __restrict__ p,
                                            const float* __restrict__ invD,
                                            float* __restrict__ A) {
  __shared__ u32 wl4[4 * 1280];              // word for e at wl4[(e&3)*1280 + (e>>2)]
  __shared__ float pl[16];
  int t = threadIdx.x;
  int n0 = blockIdx.x * 16;
  int nw = blockIdx.x >> 1;
  int base = (blockIdx.x & 1) * 16;
  for (int idx = t; idx < 1280; idx += 256) {
    uint4 wv = *(const uint4*)(bitsT + (size_t)nw * EW + idx * 4);
    wl4[idx] = wv.x;
    wl4[1280 + idx] = wv.y;
    wl4[2560 + idx] = wv.z;
    wl4[3840 + idx] = wv.w;
  }
  if (t < 16) pl[t] = p[n0 + t];
  __syncthreads();
  for (int q = t; q < 1250; q += 256) {
    u32 wd0 = wl4[q];
    u32 wd1 = wl4[1280 + q];
    u32 wd2 = wl4[2560 + q];
    u32 wd3 = wl4[3840 + q];
    float4 iv = *(const float4*)(invD + q * 4);
#pragma unroll
    for (int no = 0; no < 16; ++no) {
      int bp = base + no;
      float pn = pl[no];
      f32x4 o;
      o[0] = ((wd0 >> bp) & 1u) ? pn * iv.x : 0.f;
      o[1] = ((wd1 >> bp) & 1u) ? pn * iv.y : 0.f;
      o[2] = ((wd2 >> bp) & 1u) ? pn * iv.z : 0.f;
      o[3] = ((wd3 >> bp) & 1u) ? pn * iv.w : 0.f;
      __builtin_nontemporal_store(o, (f32x4*)(A + (size_t)(n0 + no) * CE + q * 4));
    }
  }
}

extern "C" void kernel_launch(void* const* d_in, const int* in_sizes, int n_in,
                              void* d_out, int out_size, void* d_ws, size_t ws_size,
                              hipStream_t stream) {
  const float* x = (const float*)d_in[0];
  const int*   H = (const int*)d_in[1];
  const float* W = (const float*)d_in[2];
  const float* u = (const float*)d_in[3];

  float* out0 = (float*)d_out;               // [E][128]
  float* Aout = out0 + CE * CD;              // [N][E]

  // scratch in the (not-yet-written) A region of d_out:
  float* numpart = Aout;                     // [25][5120][128] = 16,384,000 f
  float* hbuf    = Aout + 16500000;          // [N][128]
  u16*   gTt     = (u16*)(Aout + 19200000);  // [625][128][32] bf16

  // buffers surviving until k_aw live in d_ws:
  float* sc     = (float*)d_ws;              // [N]
  float* mgpart = sc + 20480;                // [2500]
  float* mg     = sc + 23040;                // [1]
  float* p      = sc + 23552;                // [N]
  float* invD   = sc + 44032;                // [5120]
  float* Dp2    = sc + 49152;                // [10][5120]
  u32*   bitsT  = (u32*)(sc + 100352);       // [625][5120] = 12.8 MB

  k_h2  <<<dim3(2500),    dim3(256), 0, stream>>>(x, W, u, hbuf, sc, mgpart);
  k_max2<<<dim3(1),       dim3(256), 0, stream>>>(mgpart, mg);
  k_bits<<<dim3(1024),    dim3(256), 0, stream>>>(H, bitsT);
  k_gt  <<<dim3(625),     dim3(256), 0, stream>>>(hbuf, sc, mg, p, gTt);
  k_dred<<<dim3(20, 10),  dim3(256), 0, stream>>>(bitsT, p, Dp2);
  k_mm  <<<dim3(40, 25),  dim3(256), 0, stream>>>(bitsT, gTt, numpart);
  k_red <<<dim3(5000),    dim3(128), 0, stream>>>(numpart, Dp2, out0, invD);
  k_aw  <<<dim3(1250),    dim3(256), 0, stream>>>(bitsT, p, invD, Aout);
}

// Round 4
// 295.986 us; speedup vs baseline: 1.7485x; 1.0215x over previous
//
#include <hip/hip_runtime.h>
#include <hip/hip_bf16.h>

typedef unsigned int u32;
typedef unsigned short u16;
typedef __bf16 bf16x8 __attribute__((ext_vector_type(8)));
typedef float f32x4 __attribute__((ext_vector_type(4)));
typedef unsigned short u16x8 __attribute__((ext_vector_type(8)));
typedef int i32x4 __attribute__((ext_vector_type(4)));

union BF8 { u16x8 u; bf16x8 b; };

#define CN 20000   // rows
#define CE 5000    // hyperedges
#define CD 128     // dim
#define NW 625     // 32-row windows
#define EW 5120    // padded e stride
#define CKS 25     // n-splits in MFMA pass (25 windows = 800 rows each)

// ---------------- K1: h = x @ W.T (+ sc + per-block max), 16 rows/block ----------------
__global__ __launch_bounds__(256) void k_h(const float* __restrict__ x,
                                           const float* __restrict__ W,
                                           const float* __restrict__ u,
                                           float* __restrict__ h,
                                           float* __restrict__ sc,
                                           float* __restrict__ mgpart) {
  __shared__ __align__(16) float Wl[128 * 132];
  __shared__ float ul[128];
  __shared__ float red16[16];
  int t = threadIdx.x;
  if (t < 128) ul[t] = u[t];
  for (int j = t; j < 128 * 128; j += 256) {
    int d = j >> 7, k = j & 127;
    Wl[d * 132 + k] = W[j];
  }
  __syncthreads();
  int slot = t >> 5;                 // 0..7 -> rows 2*slot, 2*slot+1
  int dg = t & 31;                   // d-group: d = dg, dg+32, dg+64, dg+96
  int r0 = blockIdx.x * 16 + slot * 2;
  const float* x0 = x + (size_t)r0 * 128;
  const float* x1 = x0 + 128;
  float b0 = 0.f, b1 = 0.f, b2 = 0.f, b3 = 0.f;
  float c0 = 0.f, c1 = 0.f, c2 = 0.f, c3 = 0.f;
#pragma unroll 4
  for (int k = 0; k < 128; k += 4) {
    float4 w0 = *(const float4*)(Wl + dg * 132 + k);
    float4 w1 = *(const float4*)(Wl + (dg + 32) * 132 + k);
    float4 w2 = *(const float4*)(Wl + (dg + 64) * 132 + k);
    float4 w3 = *(const float4*)(Wl + (dg + 96) * 132 + k);
    float4 xa = *(const float4*)(x0 + k);
    float4 xb = *(const float4*)(x1 + k);
    b0 += xa.x * w0.x + xa.y * w0.y + xa.z * w0.z + xa.w * w0.w;
    b1 += xa.x * w1.x + xa.y * w1.y + xa.z * w1.z + xa.w * w1.w;
    b2 += xa.x * w2.x + xa.y * w2.y + xa.z * w2.z + xa.w * w2.w;
    b3 += xa.x * w3.x + xa.y * w3.y + xa.z * w3.z + xa.w * w3.w;
    c0 += xb.x * w0.x + xb.y * w0.y + xb.z * w0.z + xb.w * w0.w;
    c1 += xb.x * w1.x + xb.y * w1.y + xb.z * w1.z + xb.w * w1.w;
    c2 += xb.x * w2.x + xb.y * w2.y + xb.z * w2.z + xb.w * w2.w;
    c3 += xb.x * w3.x + xb.y * w3.y + xb.z * w3.z + xb.w * w3.w;
  }
  float* h0 = h + (size_t)r0 * 128 + dg;
  h0[0] = b0; h0[32] = b1; h0[64] = b2; h0[96] = b3;
  float* h1 = h0 + 128;
  h1[0] = c0; h1[32] = c1; h1[64] = c2; h1[96] = c3;
  float s0 = b0 * ul[dg] + b1 * ul[dg + 32] + b2 * ul[dg + 64] + b3 * ul[dg + 96];
  float s1 = c0 * ul[dg] + c1 * ul[dg + 32] + c2 * ul[dg + 64] + c3 * ul[dg + 96];
#pragma unroll
  for (int off = 16; off; off >>= 1) {
    s0 += __shfl_down(s0, off, 32);
    s1 += __shfl_down(s1, off, 32);
  }
  if (dg == 0) {
    float v0 = s0 * 0.08838834764831845f;
    float v1 = s1 * 0.08838834764831845f;
    sc[r0] = v0; sc[r0 + 1] = v1;
    red16[slot * 2] = v0; red16[slot * 2 + 1] = v1;
  }
  __syncthreads();
  if (t == 0) {
    float m = red16[0];
#pragma unroll
    for (int i = 1; i < 16; ++i) m = fmaxf(m, red16[i]);
    mgpart[blockIdx.x] = m;
  }
}

// ---------------- K2: H -> bitsT[nw][e] (bit j = row nw*32+j), 1 task/wave ----------------
__global__ __launch_bounds__(256) void k_bits(const int* __restrict__ H,
                                              u32* __restrict__ bitsT) {
  int t = threadIdx.x, w = t >> 6, l = t & 63;
  int task = blockIdx.x * 4 + w;             // 0..12499
  int nw = task / 20;
  int seg = task - nw * 20;
  int ebase = seg * 256 + l * 4;
  u32 b0 = 0, b1 = 0, b2 = 0, b3 = 0;
  if (ebase < CE) {                          // CE%4==0: all 4 comps valid
    const int* Hb = H + (size_t)nw * 32 * CE + ebase;
    i32x4 c[8];
#pragma unroll
    for (int j = 0; j < 8; ++j)
      c[j] = __builtin_nontemporal_load((const i32x4*)(Hb + (size_t)j * CE));
#pragma unroll
    for (int r = 0; r < 32; r += 8) {
      i32x4 nx[8];
      if (r + 8 < 32) {
#pragma unroll
        for (int j = 0; j < 8; ++j)
          nx[j] = __builtin_nontemporal_load((const i32x4*)(Hb + (size_t)(r + 8 + j) * CE));
      }
#pragma unroll
      for (int j = 0; j < 8; ++j) {          // H in {0,1}: bit = value
        b0 |= ((u32)c[j].x) << (r + j);
        b1 |= ((u32)c[j].y) << (r + j);
        b2 |= ((u32)c[j].z) << (r + j);
        b3 |= ((u32)c[j].w) << (r + j);
      }
      if (r + 8 < 32) {
#pragma unroll
        for (int j = 0; j < 8; ++j) c[j] = nx[j];
      }
    }
  }
  uint4 bw; bw.x = b0; bw.y = b1; bw.z = b2; bw.w = b3;
  *(uint4*)(bitsT + (size_t)nw * EW + ebase) = bw;
}

// ---------------- K3: p = exp(sc-m) (fused global max); gTt[nw][d][32] = bf16(p*h) ----------------
__global__ __launch_bounds__(256) void k_gt(const float* __restrict__ h,
                                            const float* __restrict__ sc,
                                            const float* __restrict__ mgpart,
                                            float* __restrict__ p,
                                            u16* __restrict__ gTt) {
  __shared__ __align__(16) float hl[32 * 132];
  __shared__ float pl[32];
  __shared__ float mred[4];
  int t = threadIdx.x, w = t >> 6, l = t & 63;
  int nw = blockIdx.x;
  int n0 = nw * 32;
  float m = -1e30f;
  for (int i = t; i < 1250; i += 256) m = fmaxf(m, mgpart[i]);
#pragma unroll
  for (int off = 32; off; off >>= 1) m = fmaxf(m, __shfl_down(m, off, 64));
  if (l == 0) mred[w] = m;
#pragma unroll
  for (int k = 0; k < 4; ++k) {
    int idx = t + k * 256;                   // 1024 float4 total
    int r = idx >> 5, c = idx & 31;
    *(float4*)(hl + r * 132 + c * 4) = *(const float4*)(h + (size_t)(n0 + r) * 128 + c * 4);
  }
  __syncthreads();
  m = fmaxf(fmaxf(mred[0], mred[1]), fmaxf(mred[2], mred[3]));
  if (t < 32) {
    float pv = __expf(sc[n0 + t] - m);
    pl[t] = pv;
    p[n0 + t] = pv;
  }
  __syncthreads();
  int d = t >> 1, nh = t & 1;
  u16x8 v0, v1;
#pragma unroll
  for (int i = 0; i < 8; ++i) {
    int r = nh * 16 + i;
    union { __hip_bfloat16 b; u16 s; } cv;
    cv.b = __float2bfloat16(hl[r * 132 + d] * pl[r]);
    v0[i] = cv.s;
  }
#pragma unroll
  for (int i = 0; i < 8; ++i) {
    int r = nh * 16 + 8 + i;
    union { __hip_bfloat16 b; u16 s; } cv;
    cv.b = __float2bfloat16(hl[r * 132 + d] * pl[r]);
    v1[i] = cv.s;
  }
  u16* dst = gTt + (size_t)nw * 4096 + d * 32 + nh * 16;
  *(u16x8*)dst = v0;
  *(u16x8*)(dst + 8) = v1;
}

// ---------------- K4: D partials from bitsT + p ----------------
__global__ __launch_bounds__(256) void k_dred(const u32* __restrict__ bitsT,
                                              const float* __restrict__ p,
                                              float* __restrict__ Dp2) {
  int e = blockIdx.x * 256 + threadIdx.x;    // < 5120
  int s = blockIdx.y;                        // 0..9
  int wbeg = s * 62 + (s < 5 ? s : 5);
  int wcnt = 62 + (s < 5 ? 1 : 0);
  float d = 0.f;
  for (int k = 0; k < wcnt; ++k) {
    int wi = wbeg + k;
    u32 word = bitsT[(size_t)wi * EW + e];
    const f32x4* pp = (const f32x4*)(p + wi * 32);
#pragma unroll
    for (int c = 0; c < 8; ++c) {
      f32x4 pv = pp[c];
      d += ((word >> (4 * c)) & 1u) ? pv[0] : 0.f;
      d += ((word >> (4 * c + 1)) & 1u) ? pv[1] : 0.f;
      d += ((word >> (4 * c + 2)) & 1u) ? pv[2] : 0.f;
      d += ((word >> (4 * c + 3)) & 1u) ? pv[3] : 0.f;
    }
  }
  Dp2[(size_t)s * EW + e] = d;
}

// ---------------- K5: MFMA pass, 256 e's per block ----------------
__global__ __launch_bounds__(256, 2) void k_mm(const u32* __restrict__ bitsT,
                                               const u16* __restrict__ gTt,
                                               float* __restrict__ numpart) {
  __shared__ u32 wl[256];
  __shared__ __align__(16) u16 gl[128 * 40];
  int t = threadIdx.x;
  int w = t >> 6, l = t & 63;
  int be = blockIdx.x, ks = blockIdx.y;      // be 0..19, ks 0..24
  int e0 = be * 256;

  f32x4 acc[4][8];
#pragma unroll
  for (int s = 0; s < 4; ++s)
#pragma unroll
    for (int dt = 0; dt < 8; ++dt) acc[s][dt] = (f32x4){0.f, 0.f, 0.f, 0.f};

  for (int wi = ks * 25; wi < ks * 25 + 25; ++wi) {
    if (t < 64) *(uint4*)&wl[t * 4] = *(const uint4*)(bitsT + (size_t)wi * EW + e0 + t * 4);
    {
      const u16* src = gTt + (size_t)wi * 4096 + (t >> 1) * 32 + (t & 1) * 16;
      u16x8 v0 = *(const u16x8*)src;
      u16x8 v1 = *(const u16x8*)(src + 8);
      u16* dst = gl + (t >> 1) * 40 + (t & 1) * 16;
      *(u16x8*)dst = v0;
      *(u16x8*)(dst + 8) = v1;
    }
    __syncthreads();
    int rb = (l >> 4) * 8;
    BF8 cva[4];
#pragma unroll
    for (int s = 0; s < 4; ++s) {
      u32 ws = wl[64 * w + 16 * s + (l & 15)];
#pragma unroll
      for (int jj = 0; jj < 8; ++jj)
        cva[s].u[jj] = (u16)(((ws >> (rb + jj)) & 1u) * 0x3F80u);
    }
#pragma unroll
    for (int dt = 0; dt < 8; ++dt) {
      bf16x8 bfr = *(const bf16x8*)(gl + (dt * 16 + (l & 15)) * 40 + (l >> 4) * 8);
      acc[0][dt] = __builtin_amdgcn_mfma_f32_16x16x32_bf16(cva[0].b, bfr, acc[0][dt], 0, 0, 0);
      acc[1][dt] = __builtin_amdgcn_mfma_f32_16x16x32_bf16(cva[1].b, bfr, acc[1][dt], 0, 0, 0);
      acc[2][dt] = __builtin_amdgcn_mfma_f32_16x16x32_bf16(cva[2].b, bfr, acc[2][dt], 0, 0, 0);
      acc[3][dt] = __builtin_amdgcn_mfma_f32_16x16x32_bf16(cva[3].b, bfr, acc[3][dt], 0, 0, 0);
    }
    __syncthreads();
  }
#pragma unroll
  for (int s = 0; s < 4; ++s)
#pragma unroll
    for (int dt = 0; dt < 8; ++dt)
#pragma unroll
      for (int r = 0; r < 4; ++r) {
        int e = e0 + w * 64 + s * 16 + (l >> 4) * 4 + r;
        int d = dt * 16 + (l & 15);
        numpart[((size_t)ks * EW + e) * 128 + d] = acc[s][dt][r];
      }
}

// ---------------- K6: reduce -> out0, invD ----------------
__global__ __launch_bounds__(128) void k_red(const float* __restrict__ numpart,
                                             const float* __restrict__ Dp2,
                                             float* __restrict__ out0,
                                             float* __restrict__ invD) {
  int e = blockIdx.x, d = threadIdx.x;
  float s = 0.f;
#pragma unroll
  for (int ks = 0; ks < CKS; ++ks) s += numpart[((size_t)ks * EW + e) * 128 + d];
  float D = 0.f;
#pragma unroll
  for (int q = 0; q < 10; ++q) D += Dp2[(size_t)q * EW + e];
  out0[e * 128 + d] = s / D;
  if (d == 0) invD[e] = 1.0f / D;
}

// ---------------- K7: A[n][e] = bit ? p[n]*invD[e] : 0 ----------------
__global__ __launch_bounds__(256) void k_aw(const u32* __restrict__ bitsT,
                                            const float* __restrict__ p,
                                            const float* __restrict__ invD,
                                            float* __restrict__ A) {
  __shared__ u32 wl4[4 * 1280];              // word for e at wl4[(e&3)*1280 + (e>>2)]
  __shared__ float pl[16];
  int t = threadIdx.x;
  int n0 = blockIdx.x * 16;
  int nw = blockIdx.x >> 1;
  int base = (blockIdx.x & 1) * 16;
  for (int idx = t; idx < 1280; idx += 256) {
    uint4 wv = *(const uint4*)(bitsT + (size_t)nw * EW + idx * 4);
    wl4[idx] = wv.x;
    wl4[1280 + idx] = wv.y;
    wl4[2560 + idx] = wv.z;
    wl4[3840 + idx] = wv.w;
  }
  if (t < 16) pl[t] = p[n0 + t];
  __syncthreads();
  for (int q = t; q < 1250; q += 256) {
    u32 wd0 = wl4[q];
    u32 wd1 = wl4[1280 + q];
    u32 wd2 = wl4[2560 + q];
    u32 wd3 = wl4[3840 + q];
    float4 iv = *(const float4*)(invD + q * 4);
#pragma unroll
    for (int no = 0; no < 16; ++no) {
      int bp = base + no;
      float pn = pl[no];
      f32x4 o;
      o[0] = ((wd0 >> bp) & 1u) ? pn * iv.x : 0.f;
      o[1] = ((wd1 >> bp) & 1u) ? pn * iv.y : 0.f;
      o[2] = ((wd2 >> bp) & 1u) ? pn * iv.z : 0.f;
      o[3] = ((wd3 >> bp) & 1u) ? pn * iv.w : 0.f;
      __builtin_nontemporal_store(o, (f32x4*)(A + (size_t)(n0 + no) * CE + q * 4));
    }
  }
}

extern "C" void kernel_launch(void* const* d_in, const int* in_sizes, int n_in,
                              void* d_out, int out_size, void* d_ws, size_t ws_size,
                              hipStream_t stream) {
  const float* x = (const float*)d_in[0];
  const int*   H = (const int*)d_in[1];
  const float* W = (const float*)d_in[2];
  const float* u = (const float*)d_in[3];

  float* out0 = (float*)d_out;               // [E][128]
  float* Aout = out0 + CE * CD;              // [N][E]

  // scratch in the (not-yet-written) A region of d_out:
  float* numpart = Aout;                     // [25][5120][128] = 16,384,000 f
  float* hbuf    = Aout + 16500000;          // [N][128]
  u16*   gTt     = (u16*)(Aout + 19200000);  // [625][128][32] bf16

  // buffers surviving until k_aw live in d_ws:
  float* sc     = (float*)d_ws;              // [N]
  float* mgpart = sc + 20480;                // [1250]
  float* p      = sc + 23552;                // [N]
  float* invD   = sc + 44032;                // [5120]
  float* Dp2    = sc + 49152;                // [10][5120]
  u32*   bitsT  = (u32*)(sc + 100352);       // [625][5120] = 12.8 MB

  k_h   <<<dim3(1250),    dim3(256), 0, stream>>>(x, W, u, hbuf, sc, mgpart);
  k_bits<<<dim3(3125),    dim3(256), 0, stream>>>(H, bitsT);
  k_gt  <<<dim3(625),     dim3(256), 0, stream>>>(hbuf, sc, mgpart, p, gTt);
  k_dred<<<dim3(20, 10),  dim3(256), 0, stream>>>(bitsT, p, Dp2);
  k_mm  <<<dim3(20, 25),  dim3(256), 0, stream>>>(bitsT, gTt, numpart);
  k_red <<<dim3(5000),    dim3(128), 0, stream>>>(numpart, Dp2, out0, invD);
  k_aw  <<<dim3(1250),    dim3(256), 0, stream>>>(bitsT, p, invD, Aout);
}

// Round 5
// 254.695 us; speedup vs baseline: 2.0319x; 1.1621x over previous
//
#include <hip/hip_runtime.h>
#include <hip/hip_bf16.h>

typedef unsigned int u32;
typedef unsigned short u16;
typedef __bf16 bf16x8 __attribute__((ext_vector_type(8)));
typedef float f32x4 __attribute__((ext_vector_type(4)));
typedef unsigned short u16x8 __attribute__((ext_vector_type(8)));
typedef int i32x4 __attribute__((ext_vector_type(4)));

union BF8 { u16x8 u; bf16x8 b; };

#define CN 20000   // rows
#define CE 5000    // hyperedges
#define CD 128     // dim
#define NW 625     // 32-row windows
#define EW 5120    // padded e stride
#define CKS 25     // n-splits in MFMA pass (25 windows = 800 rows each)
#define NBITS 3125 // k_bits blocks in k_front
#define NHB 1250   // k_h blocks in k_front

// ---------------- K1: fused [H->bits streamer | x@W.T -> p, pT, gTt] ----------------
__global__ __launch_bounds__(256) void k_front(const float* __restrict__ x,
                                               const float* __restrict__ W,
                                               const float* __restrict__ u,
                                               const int* __restrict__ H,
                                               float* __restrict__ p,
                                               u16* __restrict__ pT,
                                               u16* __restrict__ gTt,
                                               u32* __restrict__ bitsT) {
  __shared__ __align__(16) float smem[19200];   // 76.8 KB, used by h-branch only
  int t = threadIdx.x;
  if (blockIdx.x < NBITS) {
    // ---- H streamer: bit j of bitsT[nw][e] = H[nw*32+j][e] (H in {0,1}) ----
    int w = t >> 6, l = t & 63;
    int task = blockIdx.x * 4 + w;             // 0..12499
    int nw = task / 20;
    int seg = task - nw * 20;
    int ebase = seg * 256 + l * 4;
    u32 b0 = 0, b1 = 0, b2 = 0, b3 = 0;
    if (ebase < CE) {                          // CE%4==0: all 4 comps valid
      const int* Hb = H + (size_t)nw * 32 * CE + ebase;
      i32x4 c[8];
#pragma unroll
      for (int j = 0; j < 8; ++j)
        c[j] = __builtin_nontemporal_load((const i32x4*)(Hb + (size_t)j * CE));
#pragma unroll
      for (int r = 0; r < 32; r += 8) {
        i32x4 nx[8];
        if (r + 8 < 32) {
#pragma unroll
          for (int j = 0; j < 8; ++j)
            nx[j] = __builtin_nontemporal_load((const i32x4*)(Hb + (size_t)(r + 8 + j) * CE));
        }
#pragma unroll
        for (int j = 0; j < 8; ++j) {
          b0 |= ((u32)c[j].x) << (r + j);
          b1 |= ((u32)c[j].y) << (r + j);
          b2 |= ((u32)c[j].z) << (r + j);
          b3 |= ((u32)c[j].w) << (r + j);
        }
        if (r + 8 < 32) {
#pragma unroll
          for (int j = 0; j < 8; ++j) c[j] = nx[j];
        }
      }
    }
    uint4 bw; bw.x = b0; bw.y = b1; bw.z = b2; bw.w = b3;
    *(uint4*)(bitsT + (size_t)nw * EW + ebase) = bw;
  } else {
    // ---- h-producer: 16 rows/block; p = exp(sc) (no max-shift needed),
    //      gTt[nw][d][32] = bf16(p*h), pT[nw][32] = bf16(p) ----
    float* Wl = smem;                // [128][132]
    float* ul = smem + 16896;       // [128]
    float* hl = smem + 17024;       // [16][132]
    float* pl = smem + 19136;       // [16]
    int hb = blockIdx.x - NBITS;    // 0..1249
    if (t < 128) ul[t] = u[t];
    for (int j = t; j < 128 * 128; j += 256) {
      int d = j >> 7, k = j & 127;
      Wl[d * 132 + k] = W[j];
    }
    __syncthreads();
    int slot = t >> 5;               // 0..7 -> local rows 2*slot, 2*slot+1
    int dg = t & 31;                 // d = dg, dg+32, dg+64, dg+96
    int r0 = hb * 16 + slot * 2;
    const float* x0 = x + (size_t)r0 * 128;
    const float* x1 = x0 + 128;
    float b0 = 0.f, b1 = 0.f, b2 = 0.f, b3 = 0.f;
    float c0 = 0.f, c1 = 0.f, c2 = 0.f, c3 = 0.f;
#pragma unroll 4
    for (int k = 0; k < 128; k += 4) {
      float4 w0 = *(const float4*)(Wl + dg * 132 + k);
      float4 w1 = *(const float4*)(Wl + (dg + 32) * 132 + k);
      float4 w2 = *(const float4*)(Wl + (dg + 64) * 132 + k);
      float4 w3 = *(const float4*)(Wl + (dg + 96) * 132 + k);
      float4 xa = *(const float4*)(x0 + k);
      float4 xb = *(const float4*)(x1 + k);
      b0 += xa.x * w0.x + xa.y * w0.y + xa.z * w0.z + xa.w * w0.w;
      b1 += xa.x * w1.x + xa.y * w1.y + xa.z * w1.z + xa.w * w1.w;
      b2 += xa.x * w2.x + xa.y * w2.y + xa.z * w2.z + xa.w * w2.w;
      b3 += xa.x * w3.x + xa.y * w3.y + xa.z * w3.z + xa.w * w3.w;
      c0 += xb.x * w0.x + xb.y * w0.y + xb.z * w0.z + xb.w * w0.w;
      c1 += xb.x * w1.x + xb.y * w1.y + xb.z * w1.z + xb.w * w1.w;
      c2 += xb.x * w2.x + xb.y * w2.y + xb.z * w2.z + xb.w * w2.w;
      c3 += xb.x * w3.x + xb.y * w3.y + xb.z * w3.z + xb.w * w3.w;
    }
    int lr0 = slot * 2, lr1 = slot * 2 + 1;
    // stage h into LDS for the transpose write
    hl[lr0 * 132 + dg] = b0; hl[lr0 * 132 + dg + 32] = b1;
    hl[lr0 * 132 + dg + 64] = b2; hl[lr0 * 132 + dg + 96] = b3;
    hl[lr1 * 132 + dg] = c0; hl[lr1 * 132 + dg + 32] = c1;
    hl[lr1 * 132 + dg + 64] = c2; hl[lr1 * 132 + dg + 96] = c3;
    float s0 = b0 * ul[dg] + b1 * ul[dg + 32] + b2 * ul[dg + 64] + b3 * ul[dg + 96];
    float s1 = c0 * ul[dg] + c1 * ul[dg + 32] + c2 * ul[dg + 64] + c3 * ul[dg + 96];
#pragma unroll
    for (int off = 16; off; off >>= 1) {
      s0 += __shfl_down(s0, off, 32);
      s1 += __shfl_down(s1, off, 32);
    }
    int nw = hb >> 1;
    int base = (hb & 1) * 16;
    if (dg == 0) {
      float p0 = __expf(s0 * 0.08838834764831845f);
      float p1 = __expf(s1 * 0.08838834764831845f);
      pl[lr0] = p0; pl[lr1] = p1;
      p[r0] = p0; p[r0 + 1] = p1;
      union { __hip_bfloat16 b; u16 s; } cv;
      cv.b = __float2bfloat16(p0); pT[nw * 32 + base + lr0] = cv.s;
      cv.b = __float2bfloat16(p1); pT[nw * 32 + base + lr1] = cv.s;
    }
    __syncthreads();
    int d = t >> 1, ch = t & 1;
    u16x8 v;
#pragma unroll
    for (int i = 0; i < 8; ++i) {
      int r = ch * 8 + i;
      union { __hip_bfloat16 b; u16 s; } cv;
      cv.b = __float2bfloat16(hl[r * 132 + d] * pl[r]);
      v[i] = cv.s;
    }
    *(u16x8*)(gTt + (size_t)nw * 4096 + d * 32 + base + ch * 8) = v;
  }
}

// ---------------- K2: MFMA pass, 256 e's/block; also D via p-row tile ----------------
__global__ __launch_bounds__(256, 2) void k_mm(const u32* __restrict__ bitsT,
                                               const u16* __restrict__ gTt,
                                               const u16* __restrict__ pT,
                                               float* __restrict__ numpart,
                                               float* __restrict__ Dpart) {
  __shared__ u32 wl[256];
  __shared__ __align__(16) u16 gl[128 * 40];
  __shared__ __align__(16) u16 glp[16 * 40];
  int t = threadIdx.x;
  int w = t >> 6, l = t & 63;
  int be = blockIdx.x, ks = blockIdx.y;      // be 0..19, ks 0..24
  int e0 = be * 256;

  for (int j = t; j < 640; j += 256) glp[j] = 0;  // rows 1-15 stay zero

  f32x4 acc[4][8];
  f32x4 acc2[4];
#pragma unroll
  for (int s = 0; s < 4; ++s) {
#pragma unroll
    for (int dt = 0; dt < 8; ++dt) acc[s][dt] = (f32x4){0.f, 0.f, 0.f, 0.f};
    acc2[s] = (f32x4){0.f, 0.f, 0.f, 0.f};
  }

  for (int wi = ks * 25; wi < ks * 25 + 25; ++wi) {
    if (t < 64) *(uint4*)&wl[t * 4] = *(const uint4*)(bitsT + (size_t)wi * EW + e0 + t * 4);
    {
      const u16* src = gTt + (size_t)wi * 4096 + (t >> 1) * 32 + (t & 1) * 16;
      u16x8 v0 = *(const u16x8*)src;
      u16x8 v1 = *(const u16x8*)(src + 8);
      u16* dst = gl + (t >> 1) * 40 + (t & 1) * 16;
      *(u16x8*)dst = v0;
      *(u16x8*)(dst + 8) = v1;
    }
    if (t < 4) *(u16x8*)(glp + t * 8) = *(const u16x8*)(pT + wi * 32 + t * 8);
    __syncthreads();
    int rb = (l >> 4) * 8;
    BF8 cva[4];
#pragma unroll
    for (int s = 0; s < 4; ++s) {
      u32 ws = wl[64 * w + 16 * s + (l & 15)];
#pragma unroll
      for (int jj = 0; jj < 8; ++jj)
        cva[s].u[jj] = (u16)(((ws >> (rb + jj)) & 1u) * 0x3F80u);
    }
    bf16x8 bfp = *(const bf16x8*)(glp + (l & 15) * 40 + (l >> 4) * 8);
#pragma unroll
    for (int dt = 0; dt < 8; ++dt) {
      bf16x8 bfr = *(const bf16x8*)(gl + (dt * 16 + (l & 15)) * 40 + (l >> 4) * 8);
      acc[0][dt] = __builtin_amdgcn_mfma_f32_16x16x32_bf16(cva[0].b, bfr, acc[0][dt], 0, 0, 0);
      acc[1][dt] = __builtin_amdgcn_mfma_f32_16x16x32_bf16(cva[1].b, bfr, acc[1][dt], 0, 0, 0);
      acc[2][dt] = __builtin_amdgcn_mfma_f32_16x16x32_bf16(cva[2].b, bfr, acc[2][dt], 0, 0, 0);
      acc[3][dt] = __builtin_amdgcn_mfma_f32_16x16x32_bf16(cva[3].b, bfr, acc[3][dt], 0, 0, 0);
    }
#pragma unroll
    for (int s = 0; s < 4; ++s)
      acc2[s] = __builtin_amdgcn_mfma_f32_16x16x32_bf16(cva[s].b, bfp, acc2[s], 0, 0, 0);
    __syncthreads();
  }
#pragma unroll
  for (int s = 0; s < 4; ++s)
#pragma unroll
    for (int dt = 0; dt < 8; ++dt)
#pragma unroll
      for (int r = 0; r < 4; ++r) {
        int e = e0 + w * 64 + s * 16 + (l >> 4) * 4 + r;
        int d = dt * 16 + (l & 15);
        numpart[((size_t)ks * EW + e) * 128 + d] = acc[s][dt][r];
      }
  if ((l & 15) == 0) {
#pragma unroll
    for (int s = 0; s < 4; ++s)
#pragma unroll
      for (int r = 0; r < 4; ++r) {
        int e = e0 + w * 64 + s * 16 + (l >> 4) * 4 + r;
        Dpart[(size_t)ks * EW + e] = acc2[s][r];
      }
  }
}

// ---------------- K3: fused [invD writer | out0 reduce] ----------------
__global__ __launch_bounds__(256) void k_mid(const float* __restrict__ numpart,
                                             const float* __restrict__ Dpart,
                                             float* __restrict__ out0,
                                             float* __restrict__ invD) {
  int t = threadIdx.x;
  if (blockIdx.x < 20) {
    int e = blockIdx.x * 256 + t;            // < 5120
    float D = 0.f;
#pragma unroll
    for (int ks = 0; ks < CKS; ++ks) D += Dpart[(size_t)ks * EW + e];
    invD[e] = 1.0f / D;
  } else {
    int b = blockIdx.x - 20;                 // 0..2499
    int e = b * 2 + (t >> 7);
    int d = t & 127;
    float s = 0.f;
#pragma unroll
    for (int ks = 0; ks < CKS; ++ks) s += numpart[((size_t)ks * EW + e) * 128 + d];
    float D = 0.f;
#pragma unroll
    for (int ks = 0; ks < CKS; ++ks) D += Dpart[(size_t)ks * EW + e];
    out0[e * 128 + d] = s / D;
  }
}

// ---------------- K4: A[n][e] = bit ? p[n]*invD[e] : 0 ----------------
__global__ __launch_bounds__(256) void k_aw(const u32* __restrict__ bitsT,
                                            const float* __restrict__ p,
                                            const float* __restrict__ invD,
                                            float* __restrict__ A) {
  __shared__ u32 wl4[4 * 1280];              // word for e at wl4[(e&3)*1280 + (e>>2)]
  __shared__ float pl[16];
  int t = threadIdx.x;
  int n0 = blockIdx.x * 16;
  int nw = blockIdx.x >> 1;
  int base = (blockIdx.x & 1) * 16;
  for (int idx = t; idx < 1280; idx += 256) {
    uint4 wv = *(const uint4*)(bitsT + (size_t)nw * EW + idx * 4);
    wl4[idx] = wv.x;
    wl4[1280 + idx] = wv.y;
    wl4[2560 + idx] = wv.z;
    wl4[3840 + idx] = wv.w;
  }
  if (t < 16) pl[t] = p[n0 + t];
  __syncthreads();
  for (int q = t; q < 1250; q += 256) {
    u32 wd0 = wl4[q];
    u32 wd1 = wl4[1280 + q];
    u32 wd2 = wl4[2560 + q];
    u32 wd3 = wl4[3840 + q];
    float4 iv = *(const float4*)(invD + q * 4);
#pragma unroll
    for (int no = 0; no < 16; ++no) {
      int bp = base + no;
      float pn = pl[no];
      f32x4 o;
      o[0] = ((wd0 >> bp) & 1u) ? pn * iv.x : 0.f;
      o[1] = ((wd1 >> bp) & 1u) ? pn * iv.y : 0.f;
      o[2] = ((wd2 >> bp) & 1u) ? pn * iv.z : 0.f;
      o[3] = ((wd3 >> bp) & 1u) ? pn * iv.w : 0.f;
      __builtin_nontemporal_store(o, (f32x4*)(A + (size_t)(n0 + no) * CE + q * 4));
    }
  }
}

extern "C" void kernel_launch(void* const* d_in, const int* in_sizes, int n_in,
                              void* d_out, int out_size, void* d_ws, size_t ws_size,
                              hipStream_t stream) {
  const float* x = (const float*)d_in[0];
  const int*   H = (const int*)d_in[1];
  const float* W = (const float*)d_in[2];
  const float* u = (const float*)d_in[3];

  float* out0 = (float*)d_out;               // [E][128]
  float* Aout = out0 + CE * CD;              // [N][E]

  // scratch in the (not-yet-written) A region of d_out (read before k_aw runs):
  float* numpart = Aout;                     // [25][5120][128] = 16,384,000 f
  u16*   gTt     = (u16*)(Aout + 16500000);  // [625][128][32] bf16 (5 MB)

  // buffers surviving until k_aw live in d_ws:
  float* wsf   = (float*)d_ws;
  float* p     = wsf;                        // [20000]
  u16*   pT    = (u16*)(wsf + 20480);        // [625][32] bf16
  float* invD  = wsf + 30720;                // [5120]
  float* Dpart = wsf + 36864;                // [25][5120]
  u32*   bitsT = (u32*)(wsf + 165888);       // [625][5120] u32 = 12.8 MB

  k_front<<<dim3(NBITS + NHB), dim3(256), 0, stream>>>(x, W, u, H, p, pT, gTt, bitsT);
  k_mm   <<<dim3(20, 25),      dim3(256), 0, stream>>>(bitsT, gTt, pT, numpart, Dpart);
  k_mid  <<<dim3(2520),        dim3(256), 0, stream>>>(numpart, Dpart, out0, invD);
  k_aw   <<<dim3(1250),        dim3(256), 0, stream>>>(bitsT, p, invD, Aout);
}